// Round 7
// baseline (348.610 us; speedup 1.0000x reference)
//
#include <hip/hip_runtime.h>
#include <hip/hip_bf16.h>

typedef __attribute__((ext_vector_type(8))) short s16x8;
typedef __attribute__((ext_vector_type(4))) float f32x4;

#define MAT2M 2097152            // 2048*1024
#define PPAD 72

__device__ __forceinline__ unsigned short f2bf(float f) {
  union { float f; unsigned u; } c; c.f = f;
  unsigned u = c.u;
  unsigned r = (u + 0x7fffu + ((u >> 16) & 1u)) >> 16;
  return (unsigned short)r;
}

__device__ __forceinline__ unsigned pk2bf(float a, float b) {
  union { __hip_bfloat162 h; unsigned u; } c;
  c.h = __float22bfloat162_rn(make_float2(a, b));
  return c.u;
}

__device__ __forceinline__ float bf2f(unsigned short u) {
  union { unsigned u; float f; } c; c.u = ((unsigned)u) << 16; return c.f;
}

__device__ __forceinline__ void async16(const unsigned short* g, unsigned short* l) {
  __builtin_amdgcn_global_load_lds(
      (const __attribute__((address_space(1))) unsigned int*)g,
      (__attribute__((address_space(3))) unsigned int*)l, 16, 0, 0);
}

// stage a 64x64 bf16 tile (row stride 1024) into XOR-swizzled LDS, async.
__device__ __forceinline__ void stage64sw(const unsigned short* __restrict__ g,
                                          unsigned short* l, int wid, int ln) {
  const int rr = ln >> 3;
  const int gcol = ((ln & 7) ^ (rr & 7)) * 8;
#pragma unroll
  for (int c = 0; c < 2; ++c) {
    int r = (c * 4 + wid) * 8 + rr;
    async16(&g[(size_t)r * 1024 + gcol], &l[(c * 4 + wid) * 512 + ln * 8]);
  }
}

// ---------- all fp32->bf16 converts in one launch ----------
__global__ __launch_bounds__(256) void k_cvt_all(
    const float* __restrict__ x, const float* __restrict__ wq,
    const float* __restrict__ wk, const float* __restrict__ wv,
    const float* __restrict__ wo,
    unsigned short* __restrict__ xb, unsigned short* __restrict__ wqb,
    unsigned short* __restrict__ wkb, unsigned short* __restrict__ wvb,
    unsigned short* __restrict__ wob) {
  const int y = blockIdx.y;
  const float* in;
  unsigned short* out;
  int n;
  if (y == 0)      { in = x;  out = xb;  n = MAT2M; }
  else if (y == 1) { in = wq; out = wqb; n = 4194304; }
  else if (y == 2) { in = wk; out = wkb; n = 4194304; }
  else if (y == 3) { in = wv; out = wvb; n = 4194304; }
  else             { in = wo; out = wob; n = 1048576; }
  int i = (blockIdx.x * 256 + threadIdx.x) * 4;
  if (i < n) {
    float4 v = *(const float4*)&in[i];
    uint2 o;
    o.x = pk2bf(v.x, v.y);
    o.y = pk2bf(v.z, v.w);
    *(uint2*)&out[i] = o;
  }
}

// ---------- mean over tokens ----------
__global__ __launch_bounds__(256) void k_meanx(const float* __restrict__ x,
                                               float* __restrict__ meanx) {
  int col = blockIdx.x * 256 + threadIdx.x;
  int b = col >> 10, d = col & 1023;
  int n0 = blockIdx.y * 64;
  float s = 0.f;
  for (int n = 0; n < 64; ++n)
    s += x[(size_t)b * 1048576 + (size_t)(n0 + n) * 1024 + d];
  atomicAdd(&meanx[col], s * (1.f / 1024.f));
}

// ---------- prep: prep[0..3]=gw[s], prep[4+s*2+b]=coh, prep[12]=scale/temp*log2e
__global__ __launch_bounds__(256) void k_prep(const float* __restrict__ meanx,
                                              const float* __restrict__ Wg,
                                              const float* __restrict__ bg,
                                              const float* __restrict__ hyp,
                                              const float* __restrict__ temp_p,
                                              float* __restrict__ prep) {
  int tid = threadIdx.x;
  int p = tid >> 5, c = tid & 31;
  int s = p >> 1, b = p & 1;
  float partial = 0.f;
  for (int d = c; d < 1024; d += 32)
    partial += meanx[b * 1024 + d] * Wg[s * 1024 + d];
#pragma unroll
  for (int m = 16; m >= 1; m >>= 1) partial += __shfl_xor(partial, m, 64);
  if (c == 0) {
    float coh = 1.f / (1.f + __expf(-(partial + bg[s])));
    prep[4 + s * 2 + b] = coh;
  }
  if (tid == 0) {
    float t = temp_p[0];
    t = fminf(fmaxf(t, 0.1f), 10.f);
    float it = 1.f / t;
    float e0 = hyp[0] * it, e1 = hyp[1] * it, e2 = hyp[2] * it, e3 = hyp[3] * it;
    float mx = fmaxf(fmaxf(e0, e1), fmaxf(e2, e3));
    float x0 = __expf(e0 - mx), x1 = __expf(e1 - mx), x2 = __expf(e2 - mx), x3 = __expf(e3 - mx);
    float inv = 1.f / (x0 + x1 + x2 + x3);
    prep[0] = x0 * inv; prep[1] = x1 * inv; prep[2] = x2 * inv; prep[3] = x3 * inv;
    prep[12] = 0.125f * it * 1.44269504f;
  }
}

// ---------- Q/K projection GEMM: swapped-operand MFMA, dbuf K-loop ----------
// grid (8 n-tiles, 16 m-tiles, 8 z); z: proj = z>>2 (0=Q,1=K), s=z&3.
// Lane holds 4 consecutive output cols -> packed uint2 bf16 stores.
__global__ __launch_bounds__(256) void gemm_qk(
    const unsigned short* __restrict__ xb,
    const unsigned short* __restrict__ wqb,
    const unsigned short* __restrict__ wkb,
    const float* __restrict__ prep,
    unsigned short* __restrict__ qk) {
  __shared__ __align__(16) unsigned short As[2][128 * 64];
  __shared__ __align__(16) unsigned short Bs[2][128 * 64];
  const int tid = threadIdx.x;
  const int wid = tid >> 6, ln = tid & 63, lq = ln >> 4, lc = ln & 15;
  const int wr = wid >> 1, wc = wid & 1;
  const int z = blockIdx.z, proj = z >> 2, s = z & 3;
  const unsigned short* Bmat = (proj == 0 ? wqb : wkb) + (size_t)s * 1048576;
  const int n0 = blockIdx.x * 128, m0 = blockIdx.y * 128;
  const int sr = wid * 8 + (ln >> 3);
  const int sc = (((ln & 7) ^ ((ln >> 3) & 7))) * 8;
  const int ldsoff = wid * 512 + ln * 8;

  f32x4 acc[4][4];
#pragma unroll
  for (int a = 0; a < 4; ++a)
#pragma unroll
    for (int b4 = 0; b4 < 4; ++b4) acc[a][b4] = (f32x4){0.f, 0.f, 0.f, 0.f};

  // prologue: stage kt=0 into buffer 0
#pragma unroll
  for (int c = 0; c < 4; ++c) {
    async16(&xb[(size_t)(m0 + c * 32 + sr) * 1024 + sc], &As[0][c * 2048 + ldsoff]);
    async16(&Bmat[(size_t)(n0 + c * 32 + sr) * 1024 + sc], &Bs[0][c * 2048 + ldsoff]);
  }

  for (int kt = 0; kt < 16; ++kt) {
    const int u = kt & 1;
    __syncthreads();
    if (kt < 15) {
      const int k1 = (kt + 1) * 64;
#pragma unroll
      for (int c = 0; c < 4; ++c) {
        async16(&xb[(size_t)(m0 + c * 32 + sr) * 1024 + k1 + sc], &As[u ^ 1][c * 2048 + ldsoff]);
        async16(&Bmat[(size_t)(n0 + c * 32 + sr) * 1024 + k1 + sc], &Bs[u ^ 1][c * 2048 + ldsoff]);
      }
    }
#pragma unroll
    for (int kc = 0; kc < 2; ++kc) {
      const int slot = ((kc * 4 + lq) ^ (lc & 7)) * 8;
      s16x8 af[4], bf[4];
#pragma unroll
      for (int a = 0; a < 4; ++a)
        af[a] = *(const s16x8*)&As[u][(wr * 64 + a * 16 + lc) * 64 + slot];
#pragma unroll
      for (int b4 = 0; b4 < 4; ++b4)
        bf[b4] = *(const s16x8*)&Bs[u][(wc * 64 + b4 * 16 + lc) * 64 + slot];
#pragma unroll
      for (int a = 0; a < 4; ++a)
#pragma unroll
        for (int b4 = 0; b4 < 4; ++b4)
          acc[a][b4] = __builtin_amdgcn_mfma_f32_16x16x32_bf16(bf[b4], af[a], acc[a][b4], 0, 0, 0);
    }
  }

  const float mulv = (proj == 1) ? prep[12] : 1.0f;
  unsigned short* C = qk + (size_t)z * MAT2M;
#pragma unroll
  for (int a = 0; a < 4; ++a) {
    int row = m0 + wr * 64 + a * 16 + lc;
    unsigned short* Crow = C + (size_t)row * 1024;
#pragma unroll
    for (int b4 = 0; b4 < 4; ++b4) {
      int colbase = n0 + wc * 64 + b4 * 16 + lq * 4;
      uint2 pv;
      pv.x = pk2bf(acc[a][b4][0] * mulv, acc[a][b4][1] * mulv);
      pv.y = pk2bf(acc[a][b4][2] * mulv, acc[a][b4][3] * mulv);
      *(uint2*)&Crow[colbase] = pv;
    }
  }
}

// ---------- V projection GEMM: normal orientation, dbuf; writes vt transposed ----------
// grid (8, 16, 4 s)
__global__ __launch_bounds__(256) void gemm_v(
    const unsigned short* __restrict__ xb,
    const unsigned short* __restrict__ wvb,
    unsigned short* __restrict__ vt) {
  __shared__ __align__(16) unsigned short As[2][128 * 64];
  __shared__ __align__(16) unsigned short Bs[2][128 * 64];
  const int tid = threadIdx.x;
  const int wid = tid >> 6, ln = tid & 63, lq = ln >> 4, lc = ln & 15;
  const int wr = wid >> 1, wc = wid & 1;
  const int s = blockIdx.z;
  const unsigned short* Bmat = wvb + (size_t)s * 1048576;
  const int n0 = blockIdx.x * 128, m0 = blockIdx.y * 128;
  const int sr = wid * 8 + (ln >> 3);
  const int sc = (((ln & 7) ^ ((ln >> 3) & 7))) * 8;
  const int ldsoff = wid * 512 + ln * 8;

  f32x4 acc[4][4];
#pragma unroll
  for (int a = 0; a < 4; ++a)
#pragma unroll
    for (int b4 = 0; b4 < 4; ++b4) acc[a][b4] = (f32x4){0.f, 0.f, 0.f, 0.f};

#pragma unroll
  for (int c = 0; c < 4; ++c) {
    async16(&xb[(size_t)(m0 + c * 32 + sr) * 1024 + sc], &As[0][c * 2048 + ldsoff]);
    async16(&Bmat[(size_t)(n0 + c * 32 + sr) * 1024 + sc], &Bs[0][c * 2048 + ldsoff]);
  }

  for (int kt = 0; kt < 16; ++kt) {
    const int u = kt & 1;
    __syncthreads();
    if (kt < 15) {
      const int k1 = (kt + 1) * 64;
#pragma unroll
      for (int c = 0; c < 4; ++c) {
        async16(&xb[(size_t)(m0 + c * 32 + sr) * 1024 + k1 + sc], &As[u ^ 1][c * 2048 + ldsoff]);
        async16(&Bmat[(size_t)(n0 + c * 32 + sr) * 1024 + k1 + sc], &Bs[u ^ 1][c * 2048 + ldsoff]);
      }
    }
#pragma unroll
    for (int kc = 0; kc < 2; ++kc) {
      const int slot = ((kc * 4 + lq) ^ (lc & 7)) * 8;
      s16x8 af[4], bf[4];
#pragma unroll
      for (int a = 0; a < 4; ++a)
        af[a] = *(const s16x8*)&As[u][(wr * 64 + a * 16 + lc) * 64 + slot];
#pragma unroll
      for (int b4 = 0; b4 < 4; ++b4)
        bf[b4] = *(const s16x8*)&Bs[u][(wc * 64 + b4 * 16 + lc) * 64 + slot];
#pragma unroll
      for (int a = 0; a < 4; ++a)
#pragma unroll
        for (int b4 = 0; b4 < 4; ++b4)
          acc[a][b4] = __builtin_amdgcn_mfma_f32_16x16x32_bf16(af[a], bf[b4], acc[a][b4], 0, 0, 0);
    }
  }

  // V: write transposed per-head: vt[((s*2+b)*16+h)][dh][ii], 4 consecutive ii per lane
#pragma unroll
  for (int a = 0; a < 4; ++a) {
    int row0 = m0 + wr * 64 + a * 16 + lq * 4;
    int bb = row0 >> 10, ii = row0 & 1023;
#pragma unroll
    for (int b4 = 0; b4 < 4; ++b4) {
      int col = n0 + wc * 64 + b4 * 16 + lc;
      int head = col >> 6, dh = col & 63;
      uint2 pk;
      pk.x = pk2bf(acc[a][b4][0], acc[a][b4][1]);
      pk.y = pk2bf(acc[a][b4][2], acc[a][b4][3]);
      *(uint2*)&vt[(((size_t)((s * 2 + bb) * 16 + head)) << 16) + dh * 1024 + ii] = pk;
    }
  }
}

// ---------- attention O: one pass, S^T, dbuf single-barrier staging ----------
__global__ __launch_bounds__(256) void att_o(
    const unsigned short* __restrict__ qk,
    const unsigned short* __restrict__ vt,
    unsigned short* __restrict__ o_sb,
    float* __restrict__ linv_ws) {
  __shared__ __align__(16) unsigned short Ks[2][64 * 64];
  __shared__ __align__(16) unsigned short Vs[2][64 * 64];
  __shared__ __align__(16) unsigned short PB[8 * 16 * PPAD];

  const int tid = threadIdx.x;
  const int wid = tid >> 6, ln = tid & 63, lq = ln >> 4, lc = ln & 15;
  const int i0 = blockIdx.x * 128;
  const int h = blockIdx.y;
  const int sb = blockIdx.z, s = sb >> 1, b = sb & 1;

  const unsigned short* Qg =
      qk + (size_t)s * MAT2M + (size_t)(b * 1024 + i0 + wid * 32) * 1024 + h * 64;
  const unsigned short* Kg = qk + (size_t)(4 + s) * MAT2M + (size_t)b * 1048576 + h * 64;
  const unsigned short* Vtg = vt + (((size_t)(sb * 16 + h)) << 16);

  s16x8 qf[2][2];
#pragma unroll
  for (int g = 0; g < 2; ++g)
#pragma unroll
    for (int kc = 0; kc < 2; ++kc)
      qf[g][kc] = *(const s16x8*)&Qg[(size_t)(g * 16 + lc) * 1024 + kc * 32 + lq * 8];

  f32x4 oaccT[2][4];
#pragma unroll
  for (int g = 0; g < 2; ++g)
#pragma unroll
    for (int db = 0; db < 4; ++db) oaccT[g][db] = (f32x4){0.f, 0.f, 0.f, 0.f};
  float lsum[2] = {0.f, 0.f};
  unsigned short* PBw = PB + wid * 2 * 16 * PPAD;

  stage64sw(Kg, Ks[0], wid, ln);
  stage64sw(Vtg, Vs[0], wid, ln);

  for (int jt = 0; jt < 16; ++jt) {
    const int u = jt & 1;
    __syncthreads();
    if (jt < 15) {
      stage64sw(Kg + (size_t)(jt + 1) * 64 * 1024, Ks[u ^ 1], wid, ln);
      stage64sw(Vtg + (jt + 1) * 64, Vs[u ^ 1], wid, ln);
    }

    f32x4 st[2][4];
#pragma unroll
    for (int g = 0; g < 2; ++g)
#pragma unroll
      for (int jb = 0; jb < 4; ++jb) st[g][jb] = (f32x4){0.f, 0.f, 0.f, 0.f};
#pragma unroll
    for (int kc = 0; kc < 2; ++kc) {
      const int slot = ((kc * 4 + lq) ^ (lc & 7)) * 8;
#pragma unroll
      for (int jb = 0; jb < 4; ++jb) {
        s16x8 kf = *(const s16x8*)&Ks[u][(jb * 16 + lc) * 64 + slot];
        st[0][jb] = __builtin_amdgcn_mfma_f32_16x16x32_bf16(kf, qf[0][kc], st[0][jb], 0, 0, 0);
        st[1][jb] = __builtin_amdgcn_mfma_f32_16x16x32_bf16(kf, qf[1][kc], st[1][jb], 0, 0, 0);
      }
    }

#pragma unroll
    for (int g = 0; g < 2; ++g)
#pragma unroll
      for (int jb = 0; jb < 4; ++jb) {
        float p0 = __builtin_amdgcn_exp2f(st[g][jb][0]);
        float p1 = __builtin_amdgcn_exp2f(st[g][jb][1]);
        float p2 = __builtin_amdgcn_exp2f(st[g][jb][2]);
        float p3 = __builtin_amdgcn_exp2f(st[g][jb][3]);
        lsum[g] += (p0 + p1) + (p2 + p3);
        uint2 pv;
        pv.x = pk2bf(p0, p1);
        pv.y = pk2bf(p2, p3);
        *(uint2*)&PBw[(g * 16 + lc) * PPAD + jb * 16 + lq * 4] = pv;
      }

#pragma unroll
    for (int kc = 0; kc < 2; ++kc) {
      const int slot = ((kc * 4 + lq) ^ (lc & 7)) * 8;
      s16x8 pf0 = *(const s16x8*)&PBw[lc * PPAD + kc * 32 + lq * 8];
      s16x8 pf1 = *(const s16x8*)&PBw[(16 + lc) * PPAD + kc * 32 + lq * 8];
#pragma unroll
      for (int db = 0; db < 4; ++db) {
        s16x8 vf = *(const s16x8*)&Vs[u][(db * 16 + lc) * 64 + slot];
        oaccT[0][db] = __builtin_amdgcn_mfma_f32_16x16x32_bf16(vf, pf0, oaccT[0][db], 0, 0, 0);
        oaccT[1][db] = __builtin_amdgcn_mfma_f32_16x16x32_bf16(vf, pf1, oaccT[1][db], 0, 0, 0);
      }
    }
  }

  float invl[2];
#pragma unroll
  for (int g = 0; g < 2; ++g) {
    lsum[g] += __shfl_xor(lsum[g], 16, 64);
    lsum[g] += __shfl_xor(lsum[g], 32, 64);
    invl[g] = 1.f / lsum[g];
  }
  if (lq == 0) {
    int base = (sb * 16 + h) * 1024 + i0 + wid * 32 + lc;
    linv_ws[base] = invl[0];
    linv_ws[base + 16] = invl[1];
  }

#pragma unroll
  for (int g = 0; g < 2; ++g) {
    int i = i0 + wid * 32 + g * 16 + lc;
    unsigned short* orow =
        o_sb + (size_t)s * MAT2M + (size_t)(b * 1024 + i) * 1024 + h * 64;
#pragma unroll
    for (int db = 0; db < 4; ++db) {
      f32x4 o = oaccT[g][db] * invl[g];
      uint2 pv;
      pv.x = pk2bf(o[0], o[1]);
      pv.y = pk2bf(o[2], o[3]);
      *(uint2*)&orow[db * 16 + lq * 4] = pv;
    }
  }
}

// ---------- attention P-sum partials: pp[z][i][j] = sum_h gw[s]/H * P/l ----------
__global__ __launch_bounds__(256) void att_p(
    const unsigned short* __restrict__ qk,
    const float* __restrict__ prep,
    const float* __restrict__ linv_ws,
    float* __restrict__ pp) {
  __shared__ __align__(16) unsigned short Qs[2][128 * 64];
  __shared__ __align__(16) unsigned short Ks[2][64 * 64];
  const int tid = threadIdx.x;
  const int wid = tid >> 6, ln = tid & 63, lq = ln >> 4, lc = ln & 15;
  const int j0 = blockIdx.x * 64;
  const int i0 = blockIdx.y * 128;
  const int z = blockIdx.z, s = z >> 1, b = z & 1;
  const float wgt = prep[s] * (1.f / 16.f);

  const unsigned short* Qb = qk + (size_t)s * MAT2M + (size_t)(b * 1024 + i0) * 1024;
  const unsigned short* Kb = qk + (size_t)(4 + s) * MAT2M + (size_t)(b * 1024 + j0) * 1024;

  const int rr = ln >> 3;
  const int gcol = ((ln & 7) ^ (rr & 7)) * 8;

  f32x4 psum[2][4];
#pragma unroll
  for (int g = 0; g < 2; ++g)
#pragma unroll
    for (int jb = 0; jb < 4; ++jb) psum[g][jb] = (f32x4){0.f, 0.f, 0.f, 0.f};

#pragma unroll
  for (int c = 0; c < 4; ++c) {
    int r = (c * 4 + wid) * 8 + rr;
    async16(&Qb[(size_t)r * 1024 + gcol], &Qs[0][(c * 4 + wid) * 512 + ln * 8]);
  }
  stage64sw(Kb, Ks[0], wid, ln);

  for (int h = 0; h < 16; ++h) {
    const int u = h & 1;
    __syncthreads();
    if (h < 15) {
      const int hoff = (h + 1) * 64;
#pragma unroll
      for (int c = 0; c < 4; ++c) {
        int r = (c * 4 + wid) * 8 + rr;
        async16(&Qb[(size_t)r * 1024 + hoff + gcol], &Qs[u ^ 1][(c * 4 + wid) * 512 + ln * 8]);
      }
      stage64sw(Kb + hoff, Ks[u ^ 1], wid, ln);
    }

    s16x8 qf[2][2];
#pragma unroll
    for (int kc = 0; kc < 2; ++kc) {
      const int slot = ((kc * 4 + lq) ^ (lc & 7)) * 8;
#pragma unroll
      for (int g = 0; g < 2; ++g)
        qf[g][kc] = *(const s16x8*)&Qs[u][(wid * 32 + g * 16 + lc) * 64 + slot];
    }
    float ilr[2];
#pragma unroll
    for (int g = 0; g < 2; ++g)
      ilr[g] = wgt * linv_ws[(z * 16 + h) * 1024 + i0 + wid * 32 + g * 16 + lc];

    f32x4 st[2][4];
#pragma unroll
    for (int g = 0; g < 2; ++g)
#pragma unroll
      for (int jb = 0; jb < 4; ++jb) st[g][jb] = (f32x4){0.f, 0.f, 0.f, 0.f};
#pragma unroll
    for (int kc = 0; kc < 2; ++kc) {
      const int slot = ((kc * 4 + lq) ^ (lc & 7)) * 8;
#pragma unroll
      for (int jb = 0; jb < 4; ++jb) {
        s16x8 kf = *(const s16x8*)&Ks[u][(jb * 16 + lc) * 64 + slot];
        st[0][jb] = __builtin_amdgcn_mfma_f32_16x16x32_bf16(kf, qf[0][kc], st[0][jb], 0, 0, 0);
        st[1][jb] = __builtin_amdgcn_mfma_f32_16x16x32_bf16(kf, qf[1][kc], st[1][jb], 0, 0, 0);
      }
    }
#pragma unroll
    for (int g = 0; g < 2; ++g)
#pragma unroll
      for (int jb = 0; jb < 4; ++jb)
#pragma unroll
        for (int r = 0; r < 4; ++r)
          psum[g][jb][r] += __builtin_amdgcn_exp2f(st[g][jb][r]) * ilr[g];
  }

  float* prow = pp + (size_t)z * 1048576;
#pragma unroll
  for (int g = 0; g < 2; ++g) {
    int i = i0 + wid * 32 + g * 16 + lc;
#pragma unroll
    for (int jb = 0; jb < 4; ++jb)
      *(f32x4*)&prow[(size_t)i * 1024 + j0 + jb * 16 + lq * 4] = psum[g][jb];
  }
}

// ---------- merged reduce (y=0) + combine (y=1) ----------
__global__ __launch_bounds__(256) void k_redcomb(const float* __restrict__ pp,
                                                 const unsigned short* __restrict__ o_sb,
                                                 const float* __restrict__ prep,
                                                 float* __restrict__ out1,
                                                 unsigned short* __restrict__ comb) {
  size_t idx = ((size_t)blockIdx.x * 256 + threadIdx.x) * 4;
  if (blockIdx.y == 0) {
    int b = (int)(idx >> 20);
    size_t rem = idx & 1048575u;
    const float* base = pp + (size_t)b * 1048576 + rem;
    float4 a0 = *(const float4*)&base[0];
    float4 a1 = *(const float4*)&base[(size_t)2 * 1048576];
    float4 a2 = *(const float4*)&base[(size_t)4 * 1048576];
    float4 a3 = *(const float4*)&base[(size_t)6 * 1048576];
    float4 o;
    o.x = (a0.x + a1.x) + (a2.x + a3.x);
    o.y = (a0.y + a1.y) + (a2.y + a3.y);
    o.z = (a0.z + a1.z) + (a2.z + a3.z);
    o.w = (a0.w + a1.w) + (a2.w + a3.w);
    *(float4*)&out1[idx] = o;
  } else {
    int m = (int)(idx >> 10);
    int b = m >> 10;
    float w0 = prep[0] * prep[4 + 0 * 2 + b];
    float w1 = prep[1] * prep[4 + 1 * 2 + b];
    float w2 = prep[2] * prep[4 + 2 * 2 + b];
    float w3 = prep[3] * prep[4 + 3 * 2 + b];
    ushort4 v0 = *(const ushort4*)&o_sb[idx];
    ushort4 v1 = *(const ushort4*)&o_sb[(size_t)MAT2M + idx];
    ushort4 v2 = *(const ushort4*)&o_sb[(size_t)2 * MAT2M + idx];
    ushort4 v3 = *(const ushort4*)&o_sb[(size_t)3 * MAT2M + idx];
    float ax = w0 * bf2f(v0.x) + w1 * bf2f(v1.x) + w2 * bf2f(v2.x) + w3 * bf2f(v3.x);
    float ay = w0 * bf2f(v0.y) + w1 * bf2f(v1.y) + w2 * bf2f(v2.y) + w3 * bf2f(v3.y);
    float az = w0 * bf2f(v0.z) + w1 * bf2f(v1.z) + w2 * bf2f(v2.z) + w3 * bf2f(v3.z);
    float aw = w0 * bf2f(v0.w) + w1 * bf2f(v1.w) + w2 * bf2f(v2.w) + w3 * bf2f(v3.w);
    uint2 o;
    o.x = pk2bf(ax, ay);
    o.y = pk2bf(az, aw);
    *(uint2*)&comb[idx] = o;
  }
}

// ---------- final GEMM: y = comb @ Wo^T + bo; swapped orientation, float4 stores ----------
__global__ __launch_bounds__(256) void gemm_out(
    const unsigned short* __restrict__ Amat,
    const unsigned short* __restrict__ Bmat,
    const float* __restrict__ bias,
    float* __restrict__ y) {
  __shared__ __align__(16) unsigned short As[2][128 * 64];
  __shared__ __align__(16) unsigned short Bs[2][128 * 64];
  const int tid = threadIdx.x;
  const int wid = tid >> 6, ln = tid & 63, lq = ln >> 4, lc = ln & 15;
  const int wr = wid >> 1, wc = wid & 1;
  const int n0 = blockIdx.x * 128, m0 = blockIdx.y * 128;
  const int sr = wid * 8 + (ln >> 3);
  const int sc = (((ln & 7) ^ ((ln >> 3) & 7))) * 8;
  const int ldsoff = wid * 512 + ln * 8;

  f32x4 acc[4][4];
#pragma unroll
  for (int a = 0; a < 4; ++a)
#pragma unroll
    for (int b4 = 0; b4 < 4; ++b4) acc[a][b4] = (f32x4){0.f, 0.f, 0.f, 0.f};

#pragma unroll
  for (int c = 0; c < 4; ++c) {
    async16(&Amat[(size_t)(m0 + c * 32 + sr) * 1024 + sc], &As[0][c * 2048 + ldsoff]);
    async16(&Bmat[(size_t)(n0 + c * 32 + sr) * 1024 + sc], &Bs[0][c * 2048 + ldsoff]);
  }

  for (int kt = 0; kt < 16; ++kt) {
    const int u = kt & 1;
    __syncthreads();
    if (kt < 15) {
      const int k1 = (kt + 1) * 64;
#pragma unroll
      for (int c = 0; c < 4; ++c) {
        async16(&Amat[(size_t)(m0 + c * 32 + sr) * 1024 + k1 + sc], &As[u ^ 1][c * 2048 + ldsoff]);
        async16(&Bmat[(size_t)(n0 + c * 32 + sr) * 1024 + k1 + sc], &Bs[u ^ 1][c * 2048 + ldsoff]);
      }
    }
#pragma unroll
    for (int kc = 0; kc < 2; ++kc) {
      const int slot = ((kc * 4 + lq) ^ (lc & 7)) * 8;
      s16x8 af[4], bf[4];
#pragma unroll
      for (int a = 0; a < 4; ++a)
        af[a] = *(const s16x8*)&As[u][(wr * 64 + a * 16 + lc) * 64 + slot];
#pragma unroll
      for (int b4 = 0; b4 < 4; ++b4)
        bf[b4] = *(const s16x8*)&Bs[u][(wc * 64 + b4 * 16 + lc) * 64 + slot];
#pragma unroll
      for (int a = 0; a < 4; ++a)
#pragma unroll
        for (int b4 = 0; b4 < 4; ++b4)
          acc[a][b4] = __builtin_amdgcn_mfma_f32_16x16x32_bf16(bf[b4], af[a], acc[a][b4], 0, 0, 0);
    }
  }

#pragma unroll
  for (int a = 0; a < 4; ++a) {
    int row = m0 + wr * 64 + a * 16 + lc;
    float* yrow = y + (size_t)row * 1024;
#pragma unroll
    for (int b4 = 0; b4 < 4; ++b4) {
      int colbase = n0 + wc * 64 + b4 * 16 + lq * 4;
      float4 bv = *(const float4*)&bias[colbase];
      float4 o;
      o.x = acc[a][b4][0] + bv.x;
      o.y = acc[a][b4][1] + bv.y;
      o.z = acc[a][b4][2] + bv.z;
      o.w = acc[a][b4][3] + bv.w;
      *(float4*)&yrow[colbase] = o;
    }
  }
}

extern "C" void kernel_launch(void* const* d_in, const int* in_sizes, int n_in,
                              void* d_out, int out_size, void* d_ws, size_t ws_size,
                              hipStream_t stream) {
  const float* x    = (const float*)d_in[0];
  const float* Wq   = (const float*)d_in[1];
  const float* Wk   = (const float*)d_in[2];
  const float* Wv   = (const float*)d_in[3];
  const float* Wg   = (const float*)d_in[4];
  const float* bg   = (const float*)d_in[5];
  const float* Wo   = (const float*)d_in[6];
  const float* bo   = (const float*)d_in[7];
  const float* hyp  = (const float*)d_in[8];
  const float* temp = (const float*)d_in[9];

  float* y = (float*)d_out;              // [2,1024,1024]
  float* out1 = y + MAT2M;               // [2,1024,1024]

  char* w = (char*)d_ws;
  size_t off = 0;
  auto alloc = [&](size_t bytes) { void* p = w + off; off += (bytes + 255) & ~(size_t)255; return p; };
  unsigned short* xb   = (unsigned short*)alloc((size_t)MAT2M * 2);
  unsigned short* wqb  = (unsigned short*)alloc((size_t)4 * 1048576 * 2);
  unsigned short* wkb  = (unsigned short*)alloc((size_t)4 * 1048576 * 2);
  unsigned short* wvb  = (unsigned short*)alloc((size_t)4 * 1048576 * 2);
  unsigned short* wob  = (unsigned short*)alloc((size_t)1048576 * 2);
  unsigned short* qk   = (unsigned short*)alloc((size_t)8 * MAT2M * 2);
  unsigned short* vt   = (unsigned short*)alloc((size_t)4 * MAT2M * 2);
  unsigned short* o_sb = (unsigned short*)alloc((size_t)4 * MAT2M * 2);
  unsigned short* comb = (unsigned short*)alloc((size_t)MAT2M * 2);
  float* pp    = (float*)alloc((size_t)8 * 1048576 * 4);
  float* linv  = (float*)alloc((size_t)131072 * 4);
  float* meanx = (float*)alloc((size_t)2048 * 4);
  float* prep  = (float*)alloc((size_t)16 * 4);

  k_cvt_all<<<dim3(4096, 5), 256, 0, stream>>>(x, Wq, Wk, Wv, Wo,
                                               xb, wqb, wkb, wvb, wob);

  hipMemsetAsync(meanx, 0, 2048 * sizeof(float), stream);
  k_meanx<<<dim3(8, 16), 256, 0, stream>>>(x, meanx);
  k_prep<<<1, 256, 0, stream>>>(meanx, Wg, bg, hyp, temp, prep);

  gemm_qk<<<dim3(8, 16, 8), 256, 0, stream>>>(xb, wqb, wkb, prep, qk);
  gemm_v<<<dim3(8, 16, 4), 256, 0, stream>>>(xb, wvb, vt);

  att_o<<<dim3(8, 16, 8), 256, 0, stream>>>(qk, vt, o_sb, linv);
  att_p<<<dim3(16, 8, 8), 256, 0, stream>>>(qk, prep, linv, pp);

  k_redcomb<<<dim3(2048, 2), 256, 0, stream>>>(pp, o_sb, prep, out1, comb);
  gemm_out<<<dim3(8, 16, 1), 256, 0, stream>>>(comb, wob, bo, y);
}

// Round 8
// 340.357 us; speedup vs baseline: 1.0242x; 1.0242x over previous
//
#include <hip/hip_runtime.h>
#include <hip/hip_bf16.h>

typedef __attribute__((ext_vector_type(8))) short s16x8;
typedef __attribute__((ext_vector_type(4))) float f32x4;

#define MAT2M 2097152            // 2048*1024

__device__ __forceinline__ unsigned short f2bf(float f) {
  union { float f; unsigned u; } c; c.f = f;
  unsigned u = c.u;
  unsigned r = (u + 0x7fffu + ((u >> 16) & 1u)) >> 16;
  return (unsigned short)r;
}

__device__ __forceinline__ unsigned pk2bf(float a, float b) {
  union { __hip_bfloat162 h; unsigned u; } c;
  c.h = __float22bfloat162_rn(make_float2(a, b));
  return c.u;
}

__device__ __forceinline__ float bf2f(unsigned short u) {
  union { unsigned u; float f; } c; c.u = ((unsigned)u) << 16; return c.f;
}

__device__ __forceinline__ void async16(const unsigned short* g, unsigned short* l) {
  __builtin_amdgcn_global_load_lds(
      (const __attribute__((address_space(1))) unsigned int*)g,
      (__attribute__((address_space(3))) unsigned int*)l, 16, 0, 0);
}

// stage a 64x64 bf16 tile (row stride 1024) into XOR-swizzled LDS, async.
__device__ __forceinline__ void stage64sw(const unsigned short* __restrict__ g,
                                          unsigned short* l, int wid, int ln) {
  const int rr = ln >> 3;
  const int gcol = ((ln & 7) ^ (rr & 7)) * 8;
#pragma unroll
  for (int c = 0; c < 2; ++c) {
    int r = (c * 4 + wid) * 8 + rr;
    async16(&g[(size_t)r * 1024 + gcol], &l[(c * 4 + wid) * 512 + ln * 8]);
  }
}

// ---------- all fp32->bf16 converts in one launch ----------
__global__ __launch_bounds__(256) void k_cvt_all(
    const float* __restrict__ x, const float* __restrict__ wq,
    const float* __restrict__ wk, const float* __restrict__ wv,
    const float* __restrict__ wo,
    unsigned short* __restrict__ xb, unsigned short* __restrict__ wqb,
    unsigned short* __restrict__ wkb, unsigned short* __restrict__ wvb,
    unsigned short* __restrict__ wob) {
  const int y = blockIdx.y;
  const float* in;
  unsigned short* out;
  int n;
  if (y == 0)      { in = x;  out = xb;  n = MAT2M; }
  else if (y == 1) { in = wq; out = wqb; n = 4194304; }
  else if (y == 2) { in = wk; out = wkb; n = 4194304; }
  else if (y == 3) { in = wv; out = wvb; n = 4194304; }
  else             { in = wo; out = wob; n = 1048576; }
  int i = (blockIdx.x * 256 + threadIdx.x) * 4;
  if (i < n) {
    float4 v = *(const float4*)&in[i];
    uint2 o;
    o.x = pk2bf(v.x, v.y);
    o.y = pk2bf(v.z, v.w);
    *(uint2*)&out[i] = o;
  }
}

// ---------- mean over tokens ----------
__global__ __launch_bounds__(256) void k_meanx(const float* __restrict__ x,
                                               float* __restrict__ meanx) {
  int col = blockIdx.x * 256 + threadIdx.x;
  int b = col >> 10, d = col & 1023;
  int n0 = blockIdx.y * 64;
  float s = 0.f;
  for (int n = 0; n < 64; ++n)
    s += x[(size_t)b * 1048576 + (size_t)(n0 + n) * 1024 + d];
  atomicAdd(&meanx[col], s * (1.f / 1024.f));
}

// ---------- prep: prep[0..3]=gw[s], prep[4+s*2+b]=coh, prep[12]=scale/temp*log2e
__global__ __launch_bounds__(256) void k_prep(const float* __restrict__ meanx,
                                              const float* __restrict__ Wg,
                                              const float* __restrict__ bg,
                                              const float* __restrict__ hyp,
                                              const float* __restrict__ temp_p,
                                              float* __restrict__ prep) {
  int tid = threadIdx.x;
  int p = tid >> 5, c = tid & 31;
  int s = p >> 1, b = p & 1;
  float partial = 0.f;
  for (int d = c; d < 1024; d += 32)
    partial += meanx[b * 1024 + d] * Wg[s * 1024 + d];
#pragma unroll
  for (int m = 16; m >= 1; m >>= 1) partial += __shfl_xor(partial, m, 64);
  if (c == 0) {
    float coh = 1.f / (1.f + __expf(-(partial + bg[s])));
    prep[4 + s * 2 + b] = coh;
  }
  if (tid == 0) {
    float t = temp_p[0];
    t = fminf(fmaxf(t, 0.1f), 10.f);
    float it = 1.f / t;
    float e0 = hyp[0] * it, e1 = hyp[1] * it, e2 = hyp[2] * it, e3 = hyp[3] * it;
    float mx = fmaxf(fmaxf(e0, e1), fmaxf(e2, e3));
    float x0 = __expf(e0 - mx), x1 = __expf(e1 - mx), x2 = __expf(e2 - mx), x3 = __expf(e3 - mx);
    float inv = 1.f / (x0 + x1 + x2 + x3);
    prep[0] = x0 * inv; prep[1] = x1 * inv; prep[2] = x2 * inv; prep[3] = x3 * inv;
    prep[12] = 0.125f * it * 1.44269504f;
  }
}

// ---------- Q/K projection GEMM: swapped-operand MFMA, dbuf K-loop ----------
__global__ __launch_bounds__(256) void gemm_qk(
    const unsigned short* __restrict__ xb,
    const unsigned short* __restrict__ wqb,
    const unsigned short* __restrict__ wkb,
    const float* __restrict__ prep,
    unsigned short* __restrict__ qk) {
  __shared__ __align__(16) unsigned short As[2][128 * 64];
  __shared__ __align__(16) unsigned short Bs[2][128 * 64];
  const int tid = threadIdx.x;
  const int wid = tid >> 6, ln = tid & 63, lq = ln >> 4, lc = ln & 15;
  const int wr = wid >> 1, wc = wid & 1;
  const int z = blockIdx.z, proj = z >> 2, s = z & 3;
  const unsigned short* Bmat = (proj == 0 ? wqb : wkb) + (size_t)s * 1048576;
  const int n0 = blockIdx.x * 128, m0 = blockIdx.y * 128;
  const int sr = wid * 8 + (ln >> 3);
  const int sc = (((ln & 7) ^ ((ln >> 3) & 7))) * 8;
  const int ldsoff = wid * 512 + ln * 8;

  f32x4 acc[4][4];
#pragma unroll
  for (int a = 0; a < 4; ++a)
#pragma unroll
    for (int b4 = 0; b4 < 4; ++b4) acc[a][b4] = (f32x4){0.f, 0.f, 0.f, 0.f};

#pragma unroll
  for (int c = 0; c < 4; ++c) {
    async16(&xb[(size_t)(m0 + c * 32 + sr) * 1024 + sc], &As[0][c * 2048 + ldsoff]);
    async16(&Bmat[(size_t)(n0 + c * 32 + sr) * 1024 + sc], &Bs[0][c * 2048 + ldsoff]);
  }

  for (int kt = 0; kt < 16; ++kt) {
    const int u = kt & 1;
    __syncthreads();
    if (kt < 15) {
      const int k1 = (kt + 1) * 64;
#pragma unroll
      for (int c = 0; c < 4; ++c) {
        async16(&xb[(size_t)(m0 + c * 32 + sr) * 1024 + k1 + sc], &As[u ^ 1][c * 2048 + ldsoff]);
        async16(&Bmat[(size_t)(n0 + c * 32 + sr) * 1024 + k1 + sc], &Bs[u ^ 1][c * 2048 + ldsoff]);
      }
    }
#pragma unroll
    for (int kc = 0; kc < 2; ++kc) {
      const int slot = ((kc * 4 + lq) ^ (lc & 7)) * 8;
      s16x8 af[4], bf[4];
#pragma unroll
      for (int a = 0; a < 4; ++a)
        af[a] = *(const s16x8*)&As[u][(wr * 64 + a * 16 + lc) * 64 + slot];
#pragma unroll
      for (int b4 = 0; b4 < 4; ++b4)
        bf[b4] = *(const s16x8*)&Bs[u][(wc * 64 + b4 * 16 + lc) * 64 + slot];
#pragma unroll
      for (int a = 0; a < 4; ++a)
#pragma unroll
        for (int b4 = 0; b4 < 4; ++b4)
          acc[a][b4] = __builtin_amdgcn_mfma_f32_16x16x32_bf16(bf[b4], af[a], acc[a][b4], 0, 0, 0);
    }
  }

  const float mulv = (proj == 1) ? prep[12] : 1.0f;
  unsigned short* C = qk + (size_t)z * MAT2M;
#pragma unroll
  for (int a = 0; a < 4; ++a) {
    int row = m0 + wr * 64 + a * 16 + lc;
    unsigned short* Crow = C + (size_t)row * 1024;
#pragma unroll
    for (int b4 = 0; b4 < 4; ++b4) {
      int colbase = n0 + wc * 64 + b4 * 16 + lq * 4;
      uint2 pv;
      pv.x = pk2bf(acc[a][b4][0] * mulv, acc[a][b4][1] * mulv);
      pv.y = pk2bf(acc[a][b4][2] * mulv, acc[a][b4][3] * mulv);
      *(uint2*)&Crow[colbase] = pv;
    }
  }
}

// ---------- V projection GEMM: normal orientation, dbuf; writes vt transposed ----------
__global__ __launch_bounds__(256) void gemm_v(
    const unsigned short* __restrict__ xb,
    const unsigned short* __restrict__ wvb,
    unsigned short* __restrict__ vt) {
  __shared__ __align__(16) unsigned short As[2][128 * 64];
  __shared__ __align__(16) unsigned short Bs[2][128 * 64];
  const int tid = threadIdx.x;
  const int wid = tid >> 6, ln = tid & 63, lq = ln >> 4, lc = ln & 15;
  const int wr = wid >> 1, wc = wid & 1;
  const int s = blockIdx.z;
  const unsigned short* Bmat = wvb + (size_t)s * 1048576;
  const int n0 = blockIdx.x * 128, m0 = blockIdx.y * 128;
  const int sr = wid * 8 + (ln >> 3);
  const int sc = (((ln & 7) ^ ((ln >> 3) & 7))) * 8;
  const int ldsoff = wid * 512 + ln * 8;

  f32x4 acc[4][4];
#pragma unroll
  for (int a = 0; a < 4; ++a)
#pragma unroll
    for (int b4 = 0; b4 < 4; ++b4) acc[a][b4] = (f32x4){0.f, 0.f, 0.f, 0.f};

#pragma unroll
  for (int c = 0; c < 4; ++c) {
    async16(&xb[(size_t)(m0 + c * 32 + sr) * 1024 + sc], &As[0][c * 2048 + ldsoff]);
    async16(&Bmat[(size_t)(n0 + c * 32 + sr) * 1024 + sc], &Bs[0][c * 2048 + ldsoff]);
  }

  for (int kt = 0; kt < 16; ++kt) {
    const int u = kt & 1;
    __syncthreads();
    if (kt < 15) {
      const int k1 = (kt + 1) * 64;
#pragma unroll
      for (int c = 0; c < 4; ++c) {
        async16(&xb[(size_t)(m0 + c * 32 + sr) * 1024 + k1 + sc], &As[u ^ 1][c * 2048 + ldsoff]);
        async16(&Bmat[(size_t)(n0 + c * 32 + sr) * 1024 + k1 + sc], &Bs[u ^ 1][c * 2048 + ldsoff]);
      }
    }
#pragma unroll
    for (int kc = 0; kc < 2; ++kc) {
      const int slot = ((kc * 4 + lq) ^ (lc & 7)) * 8;
      s16x8 af[4], bf[4];
#pragma unroll
      for (int a = 0; a < 4; ++a)
        af[a] = *(const s16x8*)&As[u][(wr * 64 + a * 16 + lc) * 64 + slot];
#pragma unroll
      for (int b4 = 0; b4 < 4; ++b4)
        bf[b4] = *(const s16x8*)&Bs[u][(wc * 64 + b4 * 16 + lc) * 64 + slot];
#pragma unroll
      for (int a = 0; a < 4; ++a)
#pragma unroll
        for (int b4 = 0; b4 < 4; ++b4)
          acc[a][b4] = __builtin_amdgcn_mfma_f32_16x16x32_bf16(af[a], bf[b4], acc[a][b4], 0, 0, 0);
    }
  }

#pragma unroll
  for (int a = 0; a < 4; ++a) {
    int row0 = m0 + wr * 64 + a * 16 + lq * 4;
    int bb = row0 >> 10, ii = row0 & 1023;
#pragma unroll
    for (int b4 = 0; b4 < 4; ++b4) {
      int col = n0 + wc * 64 + b4 * 16 + lc;
      int head = col >> 6, dh = col & 63;
      uint2 pk;
      pk.x = pk2bf(acc[a][b4][0], acc[a][b4][1]);
      pk.y = pk2bf(acc[a][b4][2], acc[a][b4][3]);
      *(uint2*)&vt[(((size_t)((s * 2 + bb) * 16 + head)) << 16) + dh * 1024 + ii] = pk;
    }
  }
}

// ---------- attention O: one pass, S^T, dbuf staging, XCD-friendly grid ----------
// grid (x=sb 8, y=h 16, z=i-tile 8): the 8 i-tiles sharing one (h,sb) K/V tile
// land on the same XCD (ids differ by 128 ≡ 0 mod 8).
__global__ __launch_bounds__(256) void att_o(
    const unsigned short* __restrict__ qk,
    const unsigned short* __restrict__ vt,
    unsigned short* __restrict__ o_sb,
    float* __restrict__ linv_ws) {
  __shared__ __align__(16) unsigned short Ks[2][64 * 64];
  __shared__ __align__(16) unsigned short Vs[2][64 * 64];
  __shared__ __align__(16) unsigned short PB[4 * 32 * 64];   // per wave: 32 rows x 64, XOR-swizzled

  const int tid = threadIdx.x;
  const int wid = tid >> 6, ln = tid & 63, lq = ln >> 4, lc = ln & 15;
  const int i0 = blockIdx.z * 128;
  const int h = blockIdx.y;
  const int sb = blockIdx.x, s = sb >> 1, b = sb & 1;

  const unsigned short* Qg =
      qk + (size_t)s * MAT2M + (size_t)(b * 1024 + i0 + wid * 32) * 1024 + h * 64;
  const unsigned short* Kg = qk + (size_t)(4 + s) * MAT2M + (size_t)b * 1048576 + h * 64;
  const unsigned short* Vtg = vt + (((size_t)(sb * 16 + h)) << 16);

  s16x8 qf[2][2];
#pragma unroll
  for (int g = 0; g < 2; ++g)
#pragma unroll
    for (int kc = 0; kc < 2; ++kc)
      qf[g][kc] = *(const s16x8*)&Qg[(size_t)(g * 16 + lc) * 1024 + kc * 32 + lq * 8];

  f32x4 oaccT[2][4];
#pragma unroll
  for (int g = 0; g < 2; ++g)
#pragma unroll
    for (int db = 0; db < 4; ++db) oaccT[g][db] = (f32x4){0.f, 0.f, 0.f, 0.f};
  float lsum[2] = {0.f, 0.f};
  unsigned short* PBw = PB + wid * 2048;

  stage64sw(Kg, Ks[0], wid, ln);
  stage64sw(Vtg, Vs[0], wid, ln);

  for (int jt = 0; jt < 16; ++jt) {
    const int u = jt & 1;
    __syncthreads();
    if (jt < 15) {
      stage64sw(Kg + (size_t)(jt + 1) * 64 * 1024, Ks[u ^ 1], wid, ln);
      stage64sw(Vtg + (jt + 1) * 64, Vs[u ^ 1], wid, ln);
    }

    f32x4 st[2][4];
#pragma unroll
    for (int g = 0; g < 2; ++g)
#pragma unroll
      for (int jb = 0; jb < 4; ++jb) st[g][jb] = (f32x4){0.f, 0.f, 0.f, 0.f};
#pragma unroll
    for (int kc = 0; kc < 2; ++kc) {
      const int slot = ((kc * 4 + lq) ^ (lc & 7)) * 8;
#pragma unroll
      for (int jb = 0; jb < 4; ++jb) {
        s16x8 kf = *(const s16x8*)&Ks[u][(jb * 16 + lc) * 64 + slot];
        st[0][jb] = __builtin_amdgcn_mfma_f32_16x16x32_bf16(kf, qf[0][kc], st[0][jb], 0, 0, 0);
        st[1][jb] = __builtin_amdgcn_mfma_f32_16x16x32_bf16(kf, qf[1][kc], st[1][jb], 0, 0, 0);
      }
    }

    // P = exp2(S^T); swizzled PB: elem (row, col) at row*64 + ((col/8)^(row&7))*8 + col%8
#pragma unroll
    for (int g = 0; g < 2; ++g)
#pragma unroll
      for (int jb = 0; jb < 4; ++jb) {
        float p0 = __builtin_amdgcn_exp2f(st[g][jb][0]);
        float p1 = __builtin_amdgcn_exp2f(st[g][jb][1]);
        float p2 = __builtin_amdgcn_exp2f(st[g][jb][2]);
        float p3 = __builtin_amdgcn_exp2f(st[g][jb][3]);
        lsum[g] += (p0 + p1) + (p2 + p3);
        uint2 pv;
        pv.x = pk2bf(p0, p1);
        pv.y = pk2bf(p2, p3);
        *(uint2*)&PBw[(g * 16 + lc) * 64 + (((jb * 2 + (lq >> 1)) ^ (lc & 7)) * 8) + (lq & 1) * 4] = pv;
      }

#pragma unroll
    for (int kc = 0; kc < 2; ++kc) {
      const int slot = ((kc * 4 + lq) ^ (lc & 7)) * 8;
      s16x8 pf0 = *(const s16x8*)&PBw[lc * 64 + slot];
      s16x8 pf1 = *(const s16x8*)&PBw[(16 + lc) * 64 + slot];
#pragma unroll
      for (int db = 0; db < 4; ++db) {
        s16x8 vf = *(const s16x8*)&Vs[u][(db * 16 + lc) * 64 + slot];
        oaccT[0][db] = __builtin_amdgcn_mfma_f32_16x16x32_bf16(vf, pf0, oaccT[0][db], 0, 0, 0);
        oaccT[1][db] = __builtin_amdgcn_mfma_f32_16x16x32_bf16(vf, pf1, oaccT[1][db], 0, 0, 0);
      }
    }
  }

  float invl[2];
#pragma unroll
  for (int g = 0; g < 2; ++g) {
    lsum[g] += __shfl_xor(lsum[g], 16, 64);
    lsum[g] += __shfl_xor(lsum[g], 32, 64);
    invl[g] = 1.f / lsum[g];
  }
  if (lq == 0) {
    int base = (sb * 16 + h) * 1024 + i0 + wid * 32 + lc;
    linv_ws[base] = invl[0];
    linv_ws[base + 16] = invl[1];
  }

#pragma unroll
  for (int g = 0; g < 2; ++g) {
    int i = i0 + wid * 32 + g * 16 + lc;
    unsigned short* orow =
        o_sb + (size_t)s * MAT2M + (size_t)(b * 1024 + i) * 1024 + h * 64;
#pragma unroll
    for (int db = 0; db < 4; ++db) {
      f32x4 o = oaccT[g][db] * invl[g];
      uint2 pv;
      pv.x = pk2bf(o[0], o[1]);
      pv.y = pk2bf(o[2], o[3]);
      *(uint2*)&orow[db * 16 + lq * 4] = pv;
    }
  }
}

// ---------- attention P-sum partials: pp[z][i][j] = sum_h gw[s]/H * P/l ----------
// grid (x=z 8, y=i0 8, z=j0 16): K-sharers (Δid=8) and Q-sharers (Δid=64)
// both land on one XCD; per-XCD working set = one z-plane Q+K = 4 MB = L2.
__global__ __launch_bounds__(256) void att_p(
    const unsigned short* __restrict__ qk,
    const float* __restrict__ prep,
    const float* __restrict__ linv_ws,
    float* __restrict__ pp) {
  __shared__ __align__(16) unsigned short Qs[2][128 * 64];
  __shared__ __align__(16) unsigned short Ks[2][64 * 64];
  const int tid = threadIdx.x;
  const int wid = tid >> 6, ln = tid & 63, lq = ln >> 4, lc = ln & 15;
  const int j0 = blockIdx.z * 64;
  const int i0 = blockIdx.y * 128;
  const int z = blockIdx.x, s = z >> 1, b = z & 1;
  const float wgt = prep[s] * (1.f / 16.f);

  const unsigned short* Qb = qk + (size_t)s * MAT2M + (size_t)(b * 1024 + i0) * 1024;
  const unsigned short* Kb = qk + (size_t)(4 + s) * MAT2M + (size_t)(b * 1024 + j0) * 1024;

  const int rr = ln >> 3;
  const int gcol = ((ln & 7) ^ (rr & 7)) * 8;

  f32x4 psum[2][4];
#pragma unroll
  for (int g = 0; g < 2; ++g)
#pragma unroll
    for (int jb = 0; jb < 4; ++jb) psum[g][jb] = (f32x4){0.f, 0.f, 0.f, 0.f};

#pragma unroll
  for (int c = 0; c < 4; ++c) {
    int r = (c * 4 + wid) * 8 + rr;
    async16(&Qb[(size_t)r * 1024 + gcol], &Qs[0][(c * 4 + wid) * 512 + ln * 8]);
  }
  stage64sw(Kb, Ks[0], wid, ln);

  for (int h = 0; h < 16; ++h) {
    const int u = h & 1;
    __syncthreads();
    if (h < 15) {
      const int hoff = (h + 1) * 64;
#pragma unroll
      for (int c = 0; c < 4; ++c) {
        int r = (c * 4 + wid) * 8 + rr;
        async16(&Qb[(size_t)r * 1024 + hoff + gcol], &Qs[u ^ 1][(c * 4 + wid) * 512 + ln * 8]);
      }
      stage64sw(Kb + hoff, Ks[u ^ 1], wid, ln);
    }

    s16x8 qf[2][2];
#pragma unroll
    for (int kc = 0; kc < 2; ++kc) {
      const int slot = ((kc * 4 + lq) ^ (lc & 7)) * 8;
#pragma unroll
      for (int g = 0; g < 2; ++g)
        qf[g][kc] = *(const s16x8*)&Qs[u][(wid * 32 + g * 16 + lc) * 64 + slot];
    }
    float ilr[2];
#pragma unroll
    for (int g = 0; g < 2; ++g)
      ilr[g] = wgt * linv_ws[(z * 16 + h) * 1024 + i0 + wid * 32 + g * 16 + lc];

    f32x4 st[2][4];
#pragma unroll
    for (int g = 0; g < 2; ++g)
#pragma unroll
      for (int jb = 0; jb < 4; ++jb) st[g][jb] = (f32x4){0.f, 0.f, 0.f, 0.f};
#pragma unroll
    for (int kc = 0; kc < 2; ++kc) {
      const int slot = ((kc * 4 + lq) ^ (lc & 7)) * 8;
#pragma unroll
      for (int jb = 0; jb < 4; ++jb) {
        s16x8 kf = *(const s16x8*)&Ks[u][(jb * 16 + lc) * 64 + slot];
        st[0][jb] = __builtin_amdgcn_mfma_f32_16x16x32_bf16(kf, qf[0][kc], st[0][jb], 0, 0, 0);
        st[1][jb] = __builtin_amdgcn_mfma_f32_16x16x32_bf16(kf, qf[1][kc], st[1][jb], 0, 0, 0);
      }
    }
#pragma unroll
    for (int g = 0; g < 2; ++g)
#pragma unroll
      for (int jb = 0; jb < 4; ++jb)
#pragma unroll
        for (int r = 0; r < 4; ++r)
          psum[g][jb][r] += __builtin_amdgcn_exp2f(st[g][jb][r]) * ilr[g];
  }

  float* prow = pp + (size_t)z * 1048576;
#pragma unroll
  for (int g = 0; g < 2; ++g) {
    int i = i0 + wid * 32 + g * 16 + lc;
#pragma unroll
    for (int jb = 0; jb < 4; ++jb)
      *(f32x4*)&prow[(size_t)i * 1024 + j0 + jb * 16 + lq * 4] = psum[g][jb];
  }
}

// ---------- merged reduce (y=0) + combine (y=1) ----------
__global__ __launch_bounds__(256) void k_redcomb(const float* __restrict__ pp,
                                                 const unsigned short* __restrict__ o_sb,
                                                 const float* __restrict__ prep,
                                                 float* __restrict__ out1,
                                                 unsigned short* __restrict__ comb) {
  size_t idx = ((size_t)blockIdx.x * 256 + threadIdx.x) * 4;
  if (blockIdx.y == 0) {
    int b = (int)(idx >> 20);
    size_t rem = idx & 1048575u;
    const float* base = pp + (size_t)b * 1048576 + rem;
    float4 a0 = *(const float4*)&base[0];
    float4 a1 = *(const float4*)&base[(size_t)2 * 1048576];
    float4 a2 = *(const float4*)&base[(size_t)4 * 1048576];
    float4 a3 = *(const float4*)&base[(size_t)6 * 1048576];
    float4 o;
    o.x = (a0.x + a1.x) + (a2.x + a3.x);
    o.y = (a0.y + a1.y) + (a2.y + a3.y);
    o.z = (a0.z + a1.z) + (a2.z + a3.z);
    o.w = (a0.w + a1.w) + (a2.w + a3.w);
    *(float4*)&out1[idx] = o;
  } else {
    int m = (int)(idx >> 10);
    int b = m >> 10;
    float w0 = prep[0] * prep[4 + 0 * 2 + b];
    float w1 = prep[1] * prep[4 + 1 * 2 + b];
    float w2 = prep[2] * prep[4 + 2 * 2 + b];
    float w3 = prep[3] * prep[4 + 3 * 2 + b];
    ushort4 v0 = *(const ushort4*)&o_sb[idx];
    ushort4 v1 = *(const ushort4*)&o_sb[(size_t)MAT2M + idx];
    ushort4 v2 = *(const ushort4*)&o_sb[(size_t)2 * MAT2M + idx];
    ushort4 v3 = *(const ushort4*)&o_sb[(size_t)3 * MAT2M + idx];
    float ax = w0 * bf2f(v0.x) + w1 * bf2f(v1.x) + w2 * bf2f(v2.x) + w3 * bf2f(v3.x);
    float ay = w0 * bf2f(v0.y) + w1 * bf2f(v1.y) + w2 * bf2f(v2.y) + w3 * bf2f(v3.y);
    float az = w0 * bf2f(v0.z) + w1 * bf2f(v1.z) + w2 * bf2f(v2.z) + w3 * bf2f(v3.z);
    float aw = w0 * bf2f(v0.w) + w1 * bf2f(v1.w) + w2 * bf2f(v2.w) + w3 * bf2f(v3.w);
    uint2 o;
    o.x = pk2bf(ax, ay);
    o.y = pk2bf(az, aw);
    *(uint2*)&comb[idx] = o;
  }
}

// ---------- final GEMM: y = comb @ Wo^T + bo; swapped orientation, float4 stores ----------
__global__ __launch_bounds__(256) void gemm_out(
    const unsigned short* __restrict__ Amat,
    const unsigned short* __restrict__ Bmat,
    const float* __restrict__ bias,
    float* __restrict__ y) {
  __shared__ __align__(16) unsigned short As[2][128 * 64];
  __shared__ __align__(16) unsigned short Bs[2][128 * 64];
  const int tid = threadIdx.x;
  const int wid = tid >> 6, ln = tid & 63, lq = ln >> 4, lc = ln & 15;
  const int wr = wid >> 1, wc = wid & 1;
  const int n0 = blockIdx.x * 128, m0 = blockIdx.y * 128;
  const int sr = wid * 8 + (ln >> 3);
  const int sc = (((ln & 7) ^ ((ln >> 3) & 7))) * 8;
  const int ldsoff = wid * 512 + ln * 8;

  f32x4 acc[4][4];
#pragma unroll
  for (int a = 0; a < 4; ++a)
#pragma unroll
    for (int b4 = 0; b4 < 4; ++b4) acc[a][b4] = (f32x4){0.f, 0.f, 0.f, 0.f};

#pragma unroll
  for (int c = 0; c < 4; ++c) {
    async16(&Amat[(size_t)(m0 + c * 32 + sr) * 1024 + sc], &As[0][c * 2048 + ldsoff]);
    async16(&Bmat[(size_t)(n0 + c * 32 + sr) * 1024 + sc], &Bs[0][c * 2048 + ldsoff]);
  }

  for (int kt = 0; kt < 16; ++kt) {
    const int u = kt & 1;
    __syncthreads();
    if (kt < 15) {
      const int k1 = (kt + 1) * 64;
#pragma unroll
      for (int c = 0; c < 4; ++c) {
        async16(&Amat[(size_t)(m0 + c * 32 + sr) * 1024 + k1 + sc], &As[u ^ 1][c * 2048 + ldsoff]);
        async16(&Bmat[(size_t)(n0 + c * 32 + sr) * 1024 + k1 + sc], &Bs[u ^ 1][c * 2048 + ldsoff]);
      }
    }
#pragma unroll
    for (int kc = 0; kc < 2; ++kc) {
      const int slot = ((kc * 4 + lq) ^ (lc & 7)) * 8;
      s16x8 af[4], bf[4];
#pragma unroll
      for (int a = 0; a < 4; ++a)
        af[a] = *(const s16x8*)&As[u][(wr * 64 + a * 16 + lc) * 64 + slot];
#pragma unroll
      for (int b4 = 0; b4 < 4; ++b4)
        bf[b4] = *(const s16x8*)&Bs[u][(wc * 64 + b4 * 16 + lc) * 64 + slot];
#pragma unroll
      for (int a = 0; a < 4; ++a)
#pragma unroll
        for (int b4 = 0; b4 < 4; ++b4)
          acc[a][b4] = __builtin_amdgcn_mfma_f32_16x16x32_bf16(bf[b4], af[a], acc[a][b4], 0, 0, 0);
    }
  }

#pragma unroll
  for (int a = 0; a < 4; ++a) {
    int row = m0 + wr * 64 + a * 16 + lc;
    float* yrow = y + (size_t)row * 1024;
#pragma unroll
    for (int b4 = 0; b4 < 4; ++b4) {
      int colbase = n0 + wc * 64 + b4 * 16 + lq * 4;
      float4 bv = *(const float4*)&bias[colbase];
      float4 o;
      o.x = acc[a][b4][0] + bv.x;
      o.y = acc[a][b4][1] + bv.y;
      o.z = acc[a][b4][2] + bv.z;
      o.w = acc[a][b4][3] + bv.w;
      *(float4*)&yrow[colbase] = o;
    }
  }
}

extern "C" void kernel_launch(void* const* d_in, const int* in_sizes, int n_in,
                              void* d_out, int out_size, void* d_ws, size_t ws_size,
                              hipStream_t stream) {
  const float* x    = (const float*)d_in[0];
  const float* Wq   = (const float*)d_in[1];
  const float* Wk   = (const float*)d_in[2];
  const float* Wv   = (const float*)d_in[3];
  const float* Wg   = (const float*)d_in[4];
  const float* bg   = (const float*)d_in[5];
  const float* Wo   = (const float*)d_in[6];
  const float* bo   = (const float*)d_in[7];
  const float* hyp  = (const float*)d_in[8];
  const float* temp = (const float*)d_in[9];

  float* y = (float*)d_out;              // [2,1024,1024]
  float* out1 = y + MAT2M;               // [2,1024,1024]

  char* w = (char*)d_ws;
  size_t off = 0;
  auto alloc = [&](size_t bytes) { void* p = w + off; off += (bytes + 255) & ~(size_t)255; return p; };
  unsigned short* xb   = (unsigned short*)alloc((size_t)MAT2M * 2);
  unsigned short* wqb  = (unsigned short*)alloc((size_t)4 * 1048576 * 2);
  unsigned short* wkb  = (unsigned short*)alloc((size_t)4 * 1048576 * 2);
  unsigned short* wvb  = (unsigned short*)alloc((size_t)4 * 1048576 * 2);
  unsigned short* wob  = (unsigned short*)alloc((size_t)1048576 * 2);
  unsigned short* qk   = (unsigned short*)alloc((size_t)8 * MAT2M * 2);
  unsigned short* vt   = (unsigned short*)alloc((size_t)4 * MAT2M * 2);
  unsigned short* o_sb = (unsigned short*)alloc((size_t)4 * MAT2M * 2);
  unsigned short* comb = (unsigned short*)alloc((size_t)MAT2M * 2);
  float* pp    = (float*)alloc((size_t)8 * 1048576 * 4);
  float* linv  = (float*)alloc((size_t)131072 * 4);
  float* meanx = (float*)alloc((size_t)2048 * 4);
  float* prep  = (float*)alloc((size_t)16 * 4);

  k_cvt_all<<<dim3(4096, 5), 256, 0, stream>>>(x, Wq, Wk, Wv, Wo,
                                               xb, wqb, wkb, wvb, wob);

  hipMemsetAsync(meanx, 0, 2048 * sizeof(float), stream);
  k_meanx<<<dim3(8, 16), 256, 0, stream>>>(x, meanx);
  k_prep<<<1, 256, 0, stream>>>(meanx, Wg, bg, hyp, temp, prep);

  gemm_qk<<<dim3(8, 16, 8), 256, 0, stream>>>(xb, wqb, wkb, prep, qk);
  gemm_v<<<dim3(8, 16, 4), 256, 0, stream>>>(xb, wvb, vt);

  att_o<<<dim3(8, 16, 8), 256, 0, stream>>>(qk, vt, o_sb, linv);
  att_p<<<dim3(8, 8, 16), 256, 0, stream>>>(qk, prep, linv, pp);

  k_redcomb<<<dim3(2048, 2), 256, 0, stream>>>(pp, o_sb, prep, out1, comb);
  gemm_out<<<dim3(8, 16, 1), 256, 0, stream>>>(comb, wob, bo, y);
}